// Round 2
// baseline (2236.388 us; speedup 1.0000x reference)
//
#include <hip/hip_runtime.h>
#include <cstdint>

#define BB 16
#define DD 64
#define LL 2048
#define NQ (BB*LL)          // 32768 queries
#define KK 8192             // codebook entries
#define VQ_SIZE (BB*DD*LL)  // 2097152 floats
#define CHUNK 256
#define NCH (KK/CHUNK)      // 32 chunks
#define MARGIN 3.0f

typedef __attribute__((ext_vector_type(8))) short short8;
typedef __attribute__((ext_vector_type(4))) float f32x4;

// Scratch lives inside d_out's v_q region (8 MB), overwritten by the final gather:
//   [0, 4MB)    X_bf16 [NQ][64]   (short)
//   [4MB, 8MB)  chunkMax [NQ][NCH] (float)
// d_ws: nh2[KK] f32 = -0.5*||c_k||^2  (32 KB; round-1 proved ws_size >= ~295KB)

static __device__ inline short f2bf(float f) {   // RNE f32 -> bf16
    uint32_t u = __float_as_uint(f);
    uint32_t r = (u + 0x7FFFu + ((u >> 16) & 1u)) >> 16;
    return (short)r;
}

// ---- prep: z_e [B][D][L] f32 -> X_bf16 [B*L][D], LDS-transposed ----
__global__ __launch_bounds__(256) void prep_x(const float* __restrict__ ze,
                                              short* __restrict__ xb) {
    __shared__ float t[64][65];
    const int b = blockIdx.x;          // 0..15
    const int l0 = blockIdx.y * 64;    // 32 l-tiles
    const int tid = threadIdx.x;
    #pragma unroll
    for (int it = 0; it < 4; ++it) {   // read 64x64 f32, coalesced along l
        int id = it * 256 + tid;
        int d = id >> 4;
        int lw = (id & 15) * 4;
        const float4 v = *(const float4*)(ze + ((size_t)b * DD + d) * LL + l0 + lw);
        t[d][lw + 0] = v.x; t[d][lw + 1] = v.y; t[d][lw + 2] = v.z; t[d][lw + 3] = v.w;
    }
    __syncthreads();
    #pragma unroll
    for (int it = 0; it < 2; ++it) {   // write rows q = b*2048+l0+lr (8 bf16 units)
        int id = it * 256 + tid;       // 0..511
        int lr = id >> 3;
        int u = id & 7;
        short8 o;
        #pragma unroll
        for (int e = 0; e < 8; ++e) o[e] = f2bf(t[u * 8 + e][lr]);
        *(short8*)(xb + (size_t)(b * LL + l0 + lr) * DD + u * 8) = o;
    }
}

// ---- prep: nh2[k] = -0.5 * ||c_k||^2 ----
__global__ __launch_bounds__(256) void prep_nh2(const float* __restrict__ cbf,
                                                float* __restrict__ nh2) {
    int k = blockIdx.x * 256 + threadIdx.x;
    const float4* c4 = (const float4*)(cbf + (size_t)k * DD);
    float s = 0.f;
    #pragma unroll
    for (int i = 0; i < DD / 4; ++i) {
        float4 v = c4[i];
        s += v.x * v.x + v.y * v.y + v.z * v.z + v.w * v.w;
    }
    nh2[k] = -0.5f * s;
}

// ---- Phase A: bf16 MFMA screen. Per (query, 256-code chunk): max of
//      s = dot(x,c) - 0.5||c||^2  (maximize s <=> minimize distance) ----
__global__ __launch_bounds__(256) void vq_screen(const float* __restrict__ cbf,
                                                 const float* __restrict__ nh2,
                                                 const short* __restrict__ xb,
                                                 float* __restrict__ cmax) {
    __shared__ short cbt[CHUNK * 64];   // 32KB, XOR-swizzled bf16 chunk
    __shared__ float sh2[CHUNK];        // 1KB
    const int tid = threadIdx.x;
    const int lane = tid & 63;
    const int wid = tid >> 6;
    const int kbase = blockIdx.y * CHUNK;
    const int qbase = blockIdx.x * 256 + wid * 64;
    const int r16 = lane & 15, g = lane >> 4;

    // stage codebook chunk: f32 -> bf16, swizzle 16B-unit u -> u ^ (row&7)
    #pragma unroll
    for (int it = 0; it < 8; ++it) {
        int id = it * 256 + tid;        // unit id 0..2047
        int row = id >> 3;
        int u = id & 7;
        const float4 lo = *(const float4*)(cbf + (size_t)(kbase + row) * 64 + u * 8);
        const float4 hi = *(const float4*)(cbf + (size_t)(kbase + row) * 64 + u * 8 + 4);
        short8 o;
        o[0] = f2bf(lo.x); o[1] = f2bf(lo.y); o[2] = f2bf(lo.z); o[3] = f2bf(lo.w);
        o[4] = f2bf(hi.x); o[5] = f2bf(hi.y); o[6] = f2bf(hi.z); o[7] = f2bf(hi.w);
        *(short8*)(&cbt[row * 64 + ((u ^ (row & 7)) * 8)]) = o;
    }
    sh2[tid] = nh2[kbase + tid];
    __syncthreads();

    // A fragments: 4 M-tiles (64 queries/wave) x 2 k-steps
    // layout 16x16x32: lane holds row = lane&15, k = (lane>>4)*8 .. +7 (contiguous)
    short8 a[4][2];
    #pragma unroll
    for (int t = 0; t < 4; ++t)
        #pragma unroll
        for (int ks = 0; ks < 2; ++ks)
            a[t][ks] = *(const short8*)(xb + (size_t)(qbase + t * 16 + r16) * 64 + ks * 32 + g * 8);

    float rm[4][4];
    #pragma unroll
    for (int t = 0; t < 4; ++t)
        #pragma unroll
        for (int j = 0; j < 4; ++j) rm[t][j] = -3.4e38f;

    for (int cs = 0; cs < CHUNK / 16; ++cs) {
        const int rowb = cs * 16 + r16;            // B: col(code) = lane&15
        const float nh = sh2[rowb];
        const f32x4 ci = {nh, nh, nh, nh};         // -0.5||c||^2 rides in C-init
        const short8 b0 = *(const short8*)(&cbt[rowb * 64 + ((g ^ (rowb & 7)) * 8)]);
        const short8 b1 = *(const short8*)(&cbt[rowb * 64 + (((g + 4) ^ (rowb & 7)) * 8)]);
        #pragma unroll
        for (int t = 0; t < 4; ++t) {
            f32x4 acc = __builtin_amdgcn_mfma_f32_16x16x32_bf16(a[t][0], b0, ci, 0, 0, 0);
            acc = __builtin_amdgcn_mfma_f32_16x16x32_bf16(a[t][1], b1, acc, 0, 0, 0);
            rm[t][0] = fmaxf(rm[t][0], acc[0]);
            rm[t][1] = fmaxf(rm[t][1], acc[1]);
            rm[t][2] = fmaxf(rm[t][2], acc[2]);
            rm[t][3] = fmaxf(rm[t][3], acc[3]);
        }
    }

    // reduce over the 16 code-slot lanes (xor of low 4 bits keeps group g)
    #pragma unroll
    for (int s = 1; s < 16; s <<= 1)
        #pragma unroll
        for (int t = 0; t < 4; ++t)
            #pragma unroll
            for (int j = 0; j < 4; ++j)
                rm[t][j] = fmaxf(rm[t][j], __shfl_xor(rm[t][j], s));

    if (r16 == 0) {   // D layout: row (query) = (lane>>4)*4 + reg
        #pragma unroll
        for (int t = 0; t < 4; ++t)
            #pragma unroll
            for (int j = 0; j < 4; ++j)
                cmax[(size_t)(qbase + t * 16 + g * 4 + j) * NCH + blockIdx.y] = rm[t][j];
    }
}

// ---- Phase B: exact fp32 re-rank of candidate chunks, one wave per query ----
__global__ __launch_bounds__(256) void vq_rerank(const float* __restrict__ ze,
                                                 const float* __restrict__ cbf,
                                                 const float* __restrict__ nh2,
                                                 const float* __restrict__ cmax,
                                                 float* __restrict__ oidx) {
    const int lane = threadIdx.x & 63;
    const int q = blockIdx.x * 4 + (threadIdx.x >> 6);
    const int b = q >> 11, l = q & (LL - 1);

    float v = (lane < NCH) ? cmax[(size_t)q * NCH + lane] : -3.4e38f;
    float m = v;
    #pragma unroll
    for (int s = 1; s < 64; s <<= 1) m = fmaxf(m, __shfl_xor(m, s));
    unsigned long long cand = __ballot(lane < NCH && v >= m - MARGIN);

    const float xd = ze[(size_t)b * DD * LL + (size_t)lane * LL + l];  // x[lane]
    unsigned long long best = ~0ULL;
    while (cand) {
        int t = __ffsll((long long)cand) - 1;
        cand &= cand - 1;
        int kb = t * CHUNK;
        for (int i = 0; i < CHUNK / 64; ++i) {
            int k = kb + i * 64 + lane;
            float acc = 0.f;
            #pragma unroll
            for (int d4 = 0; d4 < 16; ++d4) {
                float4 c4 = *(const float4*)(cbf + (size_t)k * DD + d4 * 4);
                acc = fmaf(__shfl(xd, d4 * 4 + 0), c4.x, acc);
                acc = fmaf(__shfl(xd, d4 * 4 + 1), c4.y, acc);
                acc = fmaf(__shfl(xd, d4 * 4 + 2), c4.z, acc);
                acc = fmaf(__shfl(xd, d4 * 4 + 3), c4.w, acc);
            }
            float val = -(acc + nh2[k]);           // = (d2 - ||x||^2)/2, order-equiv
            uint32_t u = __float_as_uint(val);
            uint32_t ub = ((int)u < 0) ? ~u : (u | 0x80000000u);  // sortable
            unsigned long long key = ((unsigned long long)ub << 32) | (unsigned)k;
            best = (key < best) ? key : best;      // ties -> lowest index
        }
    }
    #pragma unroll
    for (int s = 1; s < 64; s <<= 1) {
        unsigned long long o = __shfl_xor(best, s);
        best = (o < best) ? o : best;
    }
    if (lane == 0) oidx[q] = (float)(unsigned)(best & 0x1FFFu);
}

// ---- final gather: v_q[b][d][l] = codebook[idx[b][l]][d] (coalesced writes) ----
__global__ __launch_bounds__(256) void vq_gather(const float* __restrict__ cb,
                                                 const float* __restrict__ idxf,
                                                 float* __restrict__ vq) {
    int t = blockIdx.x * 256 + threadIdx.x;
    int l = t & (LL - 1);
    int bd = t >> 11;
    int d = bd & 63;
    int b = bd >> 6;
    int idx = (int)idxf[b * LL + l];
    vq[t] = cb[idx * DD + d];
}

extern "C" void kernel_launch(void* const* d_in, const int* in_sizes, int n_in,
                              void* d_out, int out_size, void* d_ws, size_t ws_size,
                              hipStream_t stream) {
    const float* ze = (const float*)d_in[0];   // [B, D, L] f32
    const float* cb = (const float*)d_in[1];   // [K, D] f32
    float* out = (float*)d_out;

    short* xb = (short*)d_out;                                   // [0, 4MB)
    float* cmax = (float*)((char*)d_out + (size_t)NQ * DD * 2);  // [4MB, 8MB)
    float* nh2 = (float*)d_ws;                                   // 32KB
    float* oidx = out + VQ_SIZE;

    dim3 gx(BB, LL / 64);
    prep_x<<<gx, 256, 0, stream>>>(ze, xb);
    prep_nh2<<<KK / 256, 256, 0, stream>>>(cb, nh2);

    dim3 gs(NQ / 256, NCH);
    vq_screen<<<gs, 256, 0, stream>>>(cb, nh2, xb, cmax);

    vq_rerank<<<NQ / 4, 256, 0, stream>>>(ze, cb, nh2, cmax, oidx);

    vq_gather<<<VQ_SIZE / 256, 256, 0, stream>>>(cb, oidx, out);
}

// Round 3
// 392.689 us; speedup vs baseline: 5.6951x; 5.6951x over previous
//
#include <hip/hip_runtime.h>
#include <cstdint>

#define BB 16
#define DD 64
#define LL 2048
#define NQ (BB*LL)          // 32768 queries
#define KK 8192             // codebook entries
#define VQ_SIZE (BB*DD*LL)  // 2097152 floats
#define CHUNK 256
#define NCH (KK/CHUNK)      // 32 chunks
#define MARGIN 1.0f         // > 2*eps_bf16 (~0.63 worst case)

typedef __attribute__((ext_vector_type(8))) short short8;
typedef __attribute__((ext_vector_type(4))) float f32x4;

// Scratch in d_out's v_q region (overwritten by final gather):
//   [0, 4MB)    X_bf16 [NQ][64]   (short)
//   [4MB, 8MB)  chunkMax [NQ][NCH] (float)
// d_ws: nh2[KK] f32 (32 KB)

static __device__ inline short f2bf(float f) {   // RNE f32 -> bf16
    uint32_t u = __float_as_uint(f);
    uint32_t r = (u + 0x7FFFu + ((u >> 16) & 1u)) >> 16;
    return (short)r;
}

// ---- prep: z_e [B][D][L] f32 -> X_bf16 [B*L][D], LDS-transposed ----
__global__ __launch_bounds__(256) void prep_x(const float* __restrict__ ze,
                                              short* __restrict__ xb) {
    __shared__ float t[64][65];
    const int b = blockIdx.x;
    const int l0 = blockIdx.y * 64;
    const int tid = threadIdx.x;
    #pragma unroll
    for (int it = 0; it < 4; ++it) {
        int id = it * 256 + tid;
        int d = id >> 4;
        int lw = (id & 15) * 4;
        const float4 v = *(const float4*)(ze + ((size_t)b * DD + d) * LL + l0 + lw);
        t[d][lw + 0] = v.x; t[d][lw + 1] = v.y; t[d][lw + 2] = v.z; t[d][lw + 3] = v.w;
    }
    __syncthreads();
    #pragma unroll
    for (int it = 0; it < 2; ++it) {
        int id = it * 256 + tid;
        int lr = id >> 3;
        int u = id & 7;
        short8 o;
        #pragma unroll
        for (int e = 0; e < 8; ++e) o[e] = f2bf(t[u * 8 + e][lr]);
        *(short8*)(xb + (size_t)(b * LL + l0 + lr) * DD + u * 8) = o;
    }
}

// ---- prep: nh2[k] = -0.5 * ||c_k||^2 ----
__global__ __launch_bounds__(256) void prep_nh2(const float* __restrict__ cbf,
                                                float* __restrict__ nh2) {
    int k = blockIdx.x * 256 + threadIdx.x;
    const float4* c4 = (const float4*)(cbf + (size_t)k * DD);
    float s = 0.f;
    #pragma unroll
    for (int i = 0; i < DD / 4; ++i) {
        float4 v = c4[i];
        s += v.x * v.x + v.y * v.y + v.z * v.z + v.w * v.w;
    }
    nh2[k] = -0.5f * s;
}

// ---- Phase A: bf16 MFMA screen. Per (query, 256-code chunk): max of
//      s = dot(x,c) - 0.5||c||^2 ----
__global__ __launch_bounds__(256) void vq_screen(const float* __restrict__ cbf,
                                                 const float* __restrict__ nh2,
                                                 const short* __restrict__ xb,
                                                 float* __restrict__ cmax) {
    __shared__ short cbt[CHUNK * 64];   // 32KB, XOR-swizzled bf16 chunk
    __shared__ float sh2[CHUNK];
    const int tid = threadIdx.x;
    const int lane = tid & 63;
    const int wid = tid >> 6;
    const int kbase = blockIdx.y * CHUNK;
    const int qbase = blockIdx.x * 256 + wid * 64;
    const int r16 = lane & 15, g = lane >> 4;

    #pragma unroll
    for (int it = 0; it < 8; ++it) {
        int id = it * 256 + tid;
        int row = id >> 3;
        int u = id & 7;
        const float4 lo = *(const float4*)(cbf + (size_t)(kbase + row) * 64 + u * 8);
        const float4 hi = *(const float4*)(cbf + (size_t)(kbase + row) * 64 + u * 8 + 4);
        short8 o;
        o[0] = f2bf(lo.x); o[1] = f2bf(lo.y); o[2] = f2bf(lo.z); o[3] = f2bf(lo.w);
        o[4] = f2bf(hi.x); o[5] = f2bf(hi.y); o[6] = f2bf(hi.z); o[7] = f2bf(hi.w);
        *(short8*)(&cbt[row * 64 + ((u ^ (row & 7)) * 8)]) = o;
    }
    sh2[tid] = nh2[kbase + tid];
    __syncthreads();

    short8 a[4][2];
    #pragma unroll
    for (int t = 0; t < 4; ++t)
        #pragma unroll
        for (int ks = 0; ks < 2; ++ks)
            a[t][ks] = *(const short8*)(xb + (size_t)(qbase + t * 16 + r16) * 64 + ks * 32 + g * 8);

    float rm[4][4];
    #pragma unroll
    for (int t = 0; t < 4; ++t)
        #pragma unroll
        for (int j = 0; j < 4; ++j) rm[t][j] = -3.4e38f;

    for (int cs = 0; cs < CHUNK / 16; ++cs) {
        const int rowb = cs * 16 + r16;
        const float nh = sh2[rowb];
        const f32x4 ci = {nh, nh, nh, nh};
        const short8 b0 = *(const short8*)(&cbt[rowb * 64 + ((g ^ (rowb & 7)) * 8)]);
        const short8 b1 = *(const short8*)(&cbt[rowb * 64 + (((g + 4) ^ (rowb & 7)) * 8)]);
        #pragma unroll
        for (int t = 0; t < 4; ++t) {
            f32x4 acc = __builtin_amdgcn_mfma_f32_16x16x32_bf16(a[t][0], b0, ci, 0, 0, 0);
            acc = __builtin_amdgcn_mfma_f32_16x16x32_bf16(a[t][1], b1, acc, 0, 0, 0);
            rm[t][0] = fmaxf(rm[t][0], acc[0]);
            rm[t][1] = fmaxf(rm[t][1], acc[1]);
            rm[t][2] = fmaxf(rm[t][2], acc[2]);
            rm[t][3] = fmaxf(rm[t][3], acc[3]);
        }
    }

    #pragma unroll
    for (int s = 1; s < 16; s <<= 1)
        #pragma unroll
        for (int t = 0; t < 4; ++t)
            #pragma unroll
            for (int j = 0; j < 4; ++j)
                rm[t][j] = fmaxf(rm[t][j], __shfl_xor(rm[t][j], s));

    if (r16 == 0) {
        #pragma unroll
        for (int t = 0; t < 4; ++t)
            #pragma unroll
            for (int j = 0; j < 4; ++j)
                cmax[(size_t)(qbase + t * 16 + g * 4 + j) * NCH + blockIdx.y] = rm[t][j];
    }
}

// ---- Phase B: exact fp32 re-rank. One block per query; candidate chunks
//      staged into LDS coalesced; 1 thread = 1 code; XOR-swizzled reads ----
__global__ __launch_bounds__(256) void vq_rerank(const float* __restrict__ ze,
                                                 const float* __restrict__ cbf,
                                                 const float* __restrict__ nh2,
                                                 const float* __restrict__ cmax,
                                                 float* __restrict__ oidx) {
    __shared__ __align__(16) float cs[CHUNK * 64];   // 64KB staged chunk
    __shared__ __align__(16) float xs[64];
    __shared__ unsigned long long wkey[4];
    __shared__ unsigned int candm;

    const int q = blockIdx.x;
    const int tid = threadIdx.x;
    const int b = q >> 11, l = q & (LL - 1);

    if (tid < 64) xs[tid] = ze[(size_t)b * DD * LL + (size_t)tid * LL + l];
    if (tid < 32) {
        float v = cmax[(size_t)q * NCH + tid];
        float m = v;
        #pragma unroll
        for (int s = 1; s < 32; s <<= 1) m = fmaxf(m, __shfl_xor(m, s));
        unsigned long long bal = __ballot(v >= m - MARGIN);
        if (tid == 0) candm = (unsigned)bal;
    }
    __syncthreads();

    unsigned int cand = candm;
    unsigned long long best = ~0ULL;
    while (cand) {
        int ch = __ffs(cand) - 1;
        cand &= cand - 1;
        int kb = ch * CHUNK;
        // stage: 256 rows x 16 float4 units, swizzle u -> u ^ (row&7)
        #pragma unroll
        for (int it = 0; it < 16; ++it) {
            int id = it * 256 + tid;
            int row = id >> 4;
            int u = id & 15;
            float4 v = *(const float4*)(cbf + (size_t)(kb + row) * 64 + u * 4);
            *(float4*)&cs[row * 64 + ((u ^ (row & 7)) << 2)] = v;
        }
        __syncthreads();
        float acc = 0.f;
        #pragma unroll
        for (int d4 = 0; d4 < 16; ++d4) {
            float4 c4 = *(const float4*)&cs[tid * 64 + ((d4 ^ (tid & 7)) << 2)];
            float4 xv = *(const float4*)&xs[d4 * 4];
            acc = fmaf(xv.x, c4.x, acc);
            acc = fmaf(xv.y, c4.y, acc);
            acc = fmaf(xv.z, c4.z, acc);
            acc = fmaf(xv.w, c4.w, acc);
        }
        int k = kb + tid;
        float val = -(acc + nh2[k]);           // order-equivalent to d2
        uint32_t u = __float_as_uint(val);
        uint32_t ub = ((int)u < 0) ? ~u : (u | 0x80000000u);
        unsigned long long key = ((unsigned long long)ub << 32) | (unsigned)k;
        best = (key < best) ? key : best;
        __syncthreads();   // protect cs before next restage
    }

    #pragma unroll
    for (int s = 1; s < 64; s <<= 1) {
        unsigned long long o = __shfl_xor(best, s);
        best = (o < best) ? o : best;
    }
    if ((tid & 63) == 0) wkey[tid >> 6] = best;
    __syncthreads();
    if (tid == 0) {
        unsigned long long k0 = wkey[0];
        #pragma unroll
        for (int w = 1; w < 4; ++w) k0 = (wkey[w] < k0) ? wkey[w] : k0;
        oidx[q] = (float)(unsigned)(k0 & 0x1FFFu);
    }
}

// ---- final gather: v_q[b][d][l] = codebook[idx[b][l]][d] ----
__global__ __launch_bounds__(256) void vq_gather(const float* __restrict__ cb,
                                                 const float* __restrict__ idxf,
                                                 float* __restrict__ vq) {
    int t = blockIdx.x * 256 + threadIdx.x;
    int l = t & (LL - 1);
    int bd = t >> 11;
    int d = bd & 63;
    int b = bd >> 6;
    int idx = (int)idxf[b * LL + l];
    vq[t] = cb[idx * DD + d];
}

extern "C" void kernel_launch(void* const* d_in, const int* in_sizes, int n_in,
                              void* d_out, int out_size, void* d_ws, size_t ws_size,
                              hipStream_t stream) {
    const float* ze = (const float*)d_in[0];
    const float* cb = (const float*)d_in[1];
    float* out = (float*)d_out;

    short* xb = (short*)d_out;
    float* cmax = (float*)((char*)d_out + (size_t)NQ * DD * 2);
    float* nh2 = (float*)d_ws;
    float* oidx = out + VQ_SIZE;

    dim3 gx(BB, LL / 64);
    prep_x<<<gx, 256, 0, stream>>>(ze, xb);
    prep_nh2<<<KK / 256, 256, 0, stream>>>(cb, nh2);

    dim3 gs(NQ / 256, NCH);
    vq_screen<<<gs, 256, 0, stream>>>(cb, nh2, xb, cmax);

    vq_rerank<<<NQ, 256, 0, stream>>>(ze, cb, nh2, cmax, oidx);

    vq_gather<<<VQ_SIZE / 256, 256, 0, stream>>>(cb, oidx, out);
}